// Round 6
// baseline (22.179 us; speedup 1.0000x reference)
//
#include <hip/hip_runtime.h>

#define NPROTO 20
#define SEQ_LEN 512
#define LPT 4                 // l-positions per thread
#define TPB (SEQ_LEN / LPT)   // 128 threads (2 waves), one block per batch row

// Correctly-rounded a/d via Markstein refinement, given rc = RN(1/d), nd = -d:
// q0 = RN(a*rc); r = fma(nd,q0,a) (exact); q1 = RN(q0 + r*rc) == RN(a/d).
// Bit-exact vs IEEE divide for this kernel's operand families (verified
// absmax=0 in R3/R4 over the full input set):
//  - d = 3.0f constant
//  - d = integer in [1,510], a = exact integer product < 2^18
__device__ __forceinline__ float div_exact(float a, float nd, float rc)
{
    const float q0 = a * rc;
    const float r  = fmaf(nd, q0, a);
    return fmaf(r, rc, q0);
}

// One block per batch row. Setup uses R4's PROVEN barrier-separated structure:
//   phase 1: lanes<20 compute/store full params (s_p4/s_p2/s_pi); barrier.
//   phase 2: thread 0 computes the sequential mean (XLA order) and serially
//            compacts KEPT prototypes into s_c4/s_c2 in ascending-p order
//            (accumulation rounding sequence == reference); barrier.
//   main:    dense loop over nkept; per-wave uniform left/right special-
//            ization via scalarized m (each wave spans 256 consecutive l).
// All f32 arithmetic replicates the reference's exact order/associativity.
__global__ __launch_bounds__(TPB)
void adaptive_mask_kernel(const float* __restrict__ tok,
                          const float* __restrict__ sigma,
                          const float* __restrict__ pi,
                          float* __restrict__ out)
{
    const int b = blockIdx.x;
    const int t = threadIdx.x;

    __shared__ float4 s_p4[NPROTO];   // full {m, aL, aR, rc}
    __shared__ float2 s_p2[NPROTO];   // full {msub = m-512, nden = -den}
    __shared__ float  s_pi[NPROTO];
    __shared__ float4 s_c4[NPROTO];   // compacted (kept only, ascending p)
    __shared__ float2 s_c2[NPROTO];
    __shared__ int    s_nkept;

    if (t < NPROTO) {
        const int idx = b * NPROTO + t;
        const float tk = tok[idx];
        const float sg = sigma[idx];
        const float m  = rintf(fminf(fmaxf(tk, 1.0f), 511.0f)); // round-half-even
        const float aL = (0.001f * sg) * m;                     // CVL*sigma*m
        const float aR = (0.001f * sg) * (512.0f - m);          // CVR*sigma*(512-m)
        const float den = (m == 511.0f) ? 1.0f : (511.0f - m);
        const float rc  = 1.0f / den;                           // IEEE RN(1/den)
        s_p4[t] = make_float4(m, aL, aR, rc);
        s_p2[t] = make_float2(m - 512.0f, -den);                // both exact
        s_pi[t] = pi[idx];
    }
    __syncthreads();

    if (t == 0) {
        float s = 0.0f;
        for (int p = 0; p < NPROTO; ++p) s += s_pi[p];   // sequential, like XLA
        const float mean = s / 20.0f;
        int k = 0;
        for (int p = 0; p < NPROTO; ++p) {
            if (s_pi[p] >= mean) {                       // same keep rule as ref
                s_c4[k] = s_p4[p];
                s_c2[k] = s_p2[p];
                ++k;
            }
        }
        s_nkept = k;                                     // >= 1 (max kept)
    }
    __syncthreads();

    const int nkept = __builtin_amdgcn_readfirstlane(s_nkept);
    const float C3 = 1.0f / 3.0f;      // RN(1/3)

    // l = LPT*t + j, j = 0..3 (consecutive -> one float4 store)
    const float lf0 = (float)(LPT * t);
    const float lf1 = lf0 + 1.0f;      // exact
    const float lf2 = lf0 + 2.0f;
    const float lf3 = lf0 + 3.0f;
    float acc0 = 0.f, acc1 = 0.f, acc2 = 0.f, acc3 = 0.f;

    // This wave covers l in [wlo, whi] (wave w: [256w, 256w+255]).
    // Positive IEEE floats are monotone in their uint encoding, so float
    // compares on m (in [1,511]) can be done as scalar uint compares.
    const unsigned wv    = __builtin_amdgcn_readfirstlane((unsigned)t) >> 6;
    const unsigned wlo_u = wv ? 0x43800000u /*256.0f*/ : 0x00000000u /*0.0f*/;
    const unsigned whi_u = wv ? 0x43FF8000u /*511.0f*/ : 0x437F0000u /*255.0f*/;

    #pragma unroll 1
    for (int p = 0; p < nkept; ++p) {  // ascending kept-p: order == reference
        const float4 P = s_c4[p];      // broadcast ds_read_b128
        const float2 Q = s_c2[p];      // broadcast ds_read_b64
        const float m = P.x, aL = P.y, aR = P.z, rc = P.w;
        const float msub = Q.x, nden = Q.y;
        // m is wave-uniform (same LDS word) -> scalarize for s_cbranch
        const unsigned mu = __builtin_amdgcn_readfirstlane(__float_as_uint(m));

        if (mu > whi_u) {
            // whole wave is left of m: base = ((l-m)+1) + aL
#define EVL(LF, ACC) {                                                      \
            const float q    = (LF) - m;                                    \
            const float left = (q + 1.0f) + aL;                             \
            (ACC) += div_exact(left, -3.0f, C3) + 1.0f; }
            EVL(lf0, acc0) EVL(lf1, acc1) EVL(lf2, acc2) EVL(lf3, acc3)
#undef EVL
        } else if (mu <= wlo_u) {
            // whole wave is right of m: base = (-1 + q*(m-512)/den) + aR
#define EVR(LF, ACC) {                                                      \
            const float q    = (LF) - m;                                    \
            const float num  = q * msub;            /* exact int product */ \
            const float rq   = div_exact(num, nden, rc);  /* RN(num/den) */ \
            const float rt   = (-1.0f + rq) + aR;                           \
            (ACC) += div_exact(rt, -3.0f, C3) + 1.0f; }
            EVR(lf0, acc0) EVR(lf1, acc1) EVR(lf2, acc2) EVR(lf3, acc3)
#undef EVR
        } else {
            // m splits this wave: per-lane select (proven R3/R4 path)
#define EVM(LF, ACC) {                                                      \
            const float q    = (LF) - m;                                    \
            const float num  = q * msub;                                    \
            const float rq   = div_exact(num, nden, rc);                    \
            const float left = (q + 1.0f) + aL;                             \
            const float rt   = (-1.0f + rq) + aR;                           \
            const float base = ((LF) < m) ? left : rt;                      \
            (ACC) += div_exact(base, -3.0f, C3) + 1.0f; }
            EVM(lf0, acc0) EVM(lf1, acc1) EVM(lf2, acc2) EVM(lf3, acc3)
#undef EVM
        }
    }

    float4 res;
    res.x = (acc0 > 0.0f) ? 1.0f : 0.0f;
    res.y = (acc1 > 0.0f) ? 1.0f : 0.0f;
    res.z = (acc2 > 0.0f) ? 1.0f : 0.0f;
    res.w = (acc3 > 0.0f) ? 1.0f : 0.0f;
    *reinterpret_cast<float4*>(out + (size_t)b * SEQ_LEN + LPT * t) = res;
}

extern "C" void kernel_launch(void* const* d_in, const int* in_sizes, int n_in,
                              void* d_out, int out_size, void* d_ws, size_t ws_size,
                              hipStream_t stream)
{
    const float* tok   = (const float*)d_in[0];
    const float* sigma = (const float*)d_in[1];
    const float* pi    = (const float*)d_in[2];
    float* out = (float*)d_out;

    const int B = in_sizes[0] / NPROTO;   // 8192
    adaptive_mask_kernel<<<B, TPB, 0, stream>>>(tok, sigma, pi, out);
}